// Round 1
// baseline (399.837 us; speedup 1.0000x reference)
//
#include <hip/hip_runtime.h>
#include <hip/hip_fp16.h>
#include <cstdint>

typedef _Float16 half8  __attribute__((ext_vector_type(8)));
typedef _Float16 half4v __attribute__((ext_vector_type(4)));
typedef float    floatx4 __attribute__((ext_vector_type(4)));

// problem dims (fixed by setup_inputs)
constexpr int Bb = 4, Ss = 4096, Dd = 1024;
constexpr int Mdim = Bb * Ss;          // 16384
constexpr int Ndim = 3 * Dd;           // 3072
constexpr int Kdim = Dd;               // 1024
constexpr int CH = 32, LCH = Ss / CH;  // 32 chunks of 128

// ---------------------------------------------------------------- utils
__device__ __forceinline__ void gload_lds16(const void* g, void* l) {
  __builtin_amdgcn_global_load_lds(
      (const __attribute__((address_space(1))) uint32_t*)g,
      (__attribute__((address_space(3))) uint32_t*)l, 16, 0, 0);
}

__device__ __forceinline__ float softplus_f(float x) {
  // log(1+e^x), stable both directions
  return x > 0.f ? x + log1pf(__expf(-x)) : log1pf(__expf(x));
}

// ---------------------------------------------------------------- K0a: x fp32 -> fp16
__global__ __launch_bounds__(256) void cvt_x_k(const float* __restrict__ X,
                                               _Float16* __restrict__ X16, int n4) {
  for (int i = blockIdx.x * blockDim.x + threadIdx.x; i < n4;
       i += gridDim.x * blockDim.x) {
    float4 v = ((const float4*)X)[i];
    half4v o = {(_Float16)v.x, (_Float16)v.y, (_Float16)v.z, (_Float16)v.w};
    ((half4v*)X16)[i] = o;
  }
}

// ---------------------------------------------------------------- K0b: W [K][N] fp32 -> WT [N][K] fp16
__global__ __launch_bounds__(256) void cvt_wT_k(const float* __restrict__ W,
                                                _Float16* __restrict__ WT) {
  __shared__ float tile[32][33];
  int tx = threadIdx.x & 31, ty = threadIdx.x >> 5;  // 32 x 8
  int n0 = blockIdx.x * 32, k0 = blockIdx.y * 32;
#pragma unroll
  for (int j = 0; j < 4; ++j) {
    int k = ty + j * 8;
    tile[k][tx] = W[(int64_t)(k0 + k) * Ndim + n0 + tx];
  }
  __syncthreads();
#pragma unroll
  for (int j = 0; j < 4; ++j) {
    int nl = ty + j * 8;
    WT[(int64_t)(n0 + nl) * Kdim + k0 + tx] = (_Float16)tile[tx][nl];
  }
}

// ---------------------------------------------------------------- K1: GEMM (m97 structure)
// A: x16 [M][K] fp16 row-major; BT: W16T [N][K] fp16 row-major; C: gates16 [M][N] fp16
constexpr int BM = 128, BN = 128, BK = 32;

__global__ __launch_bounds__(256, 3) void gemm_f16_k(const _Float16* __restrict__ A,
                                                     const _Float16* __restrict__ BT,
                                                     _Float16* __restrict__ Cg) {
  __shared__ _Float16 As[BM * BK];
  __shared__ _Float16 Bs[BN * BK];
  const int tid = threadIdx.x;
  const int wave = tid >> 6, lane = tid & 63;
  const int m0 = blockIdx.y * BM, n0 = blockIdx.x * BN;
  const int wm = wave >> 1, wn = wave & 1;
  const int l15 = lane & 15, lq = lane >> 4;
  const int k8 = lq * 8;

  // staging: chunk q = r*4 + wave; half base = q*512 + lane*8 (HW: base + lane*16B)
  int aIdx[2], bIdx[2], ldsOff[2];
#pragma unroll
  for (int r = 0; r < 2; ++r) {
    int q = r * 4 + wave;
    int idx = q * 512 + lane * 8;
    int row = idx >> 5, col = idx & 31;
    ldsOff[r] = q * 512;  // wave-uniform
    aIdx[r] = (m0 + row) * Kdim + col;
    bIdx[r] = (n0 + row) * Kdim + col;
  }

  // fragment LDS half-offsets
  int aoff[4], boff[4];
#pragma unroll
  for (int f = 0; f < 4; ++f) {
    aoff[f] = (wm * 64 + f * 16 + l15) * BK + k8;
    boff[f] = (wn * 64 + f * 16 + l15) * BK + k8;
  }

  floatx4 acc[4][4] = {};

  for (int kt = 0; kt < Kdim; kt += BK) {
#pragma unroll
    for (int r = 0; r < 2; ++r) {
      gload_lds16(A + aIdx[r] + kt, (void*)(As + ldsOff[r]));
      gload_lds16(BT + bIdx[r] + kt, (void*)(Bs + ldsOff[r]));
    }
    asm volatile("s_waitcnt vmcnt(0)" ::: "memory");
    __syncthreads();

    half8 bfrag[4];
#pragma unroll
    for (int f = 0; f < 4; ++f) bfrag[f] = *(const half8*)(Bs + boff[f]);
#pragma unroll
    for (int fm = 0; fm < 4; ++fm) {
      half8 afrag = *(const half8*)(As + aoff[fm]);
#pragma unroll
      for (int fn = 0; fn < 4; ++fn)
        acc[fm][fn] = __builtin_amdgcn_mfma_f32_16x16x32_f16(afrag, bfrag[fn],
                                                             acc[fm][fn], 0, 0, 0);
    }
    __syncthreads();
  }

  // epilogue: C/D layout col=lane&15, row=(lane>>4)*4+reg
#pragma unroll
  for (int fm = 0; fm < 4; ++fm) {
    int mrow = m0 + wm * 64 + fm * 16 + lq * 4;
#pragma unroll
    for (int fn = 0; fn < 4; ++fn) {
      int ncol = n0 + wn * 64 + fn * 16 + l15;
#pragma unroll
      for (int r = 0; r < 4; ++r)
        Cg[(int64_t)(mrow + r) * Ndim + ncol] = (_Float16)acc[fm][fn][r];
    }
  }
}

// ---------------------------------------------------------------- K2: gates -> f, v (fp16)
__global__ __launch_bounds__(256) void combine_k(const _Float16* __restrict__ G,
                                                 _Float16* __restrict__ F,
                                                 _Float16* __restrict__ V) {
  const int total = Mdim * (Dd / 8);  // groups of 8 along d
  for (int i = blockIdx.x * blockDim.x + threadIdx.x; i < total;
       i += gridDim.x * blockDim.x) {
    int m = i >> 7;             // Dd/8 == 128
    int d8 = (i & 127) << 3;
    const _Float16* g = G + (int64_t)m * Ndim + d8;
    half8 fg = *(const half8*)(g);
    half8 ig = *(const half8*)(g + Dd);
    half8 hg = *(const half8*)(g + 2 * Dd);
    half8 fo, vo;
#pragma unroll
    for (int j = 0; j < 8; ++j) {
      float fgv = (float)fg[j], igv = (float)ig[j], hgv = (float)hg[j];
      float diff = softplus_f(-fgv) - softplus_f(-igv);
      float fw = 1.f / (1.f + __expf(diff));    // sig(-diff) = sig(f)/(sig(f)+sig(i))
      float iw = 1.f / (1.f + __expf(-diff));   // sig(diff)
      float gt = hgv >= 0.f ? hgv + 0.5f : 1.f / (1.f + __expf(-hgv));
      fo[j] = (_Float16)fw;
      vo[j] = (_Float16)(iw * gt);
    }
    *(half8*)(F + (int64_t)m * Dd + d8) = fo;
    *(half8*)(V + (int64_t)m * Dd + d8) = vo;
  }
}

// ---------------------------------------------------------------- K3/K4/K5: chunked scan
__global__ __launch_bounds__(256) void scan1_k(const _Float16* __restrict__ F,
                                               const _Float16* __restrict__ V,
                                               float* __restrict__ Fc,
                                               float* __restrict__ Hc) {
  int d = blockIdx.x * 256 + threadIdx.x;
  int c = blockIdx.y, b = blockIdx.z;
  int64_t base = ((int64_t)b * Ss + c * LCH) * Dd + d;
  float h = 0.f, Fp = 1.f;
#pragma unroll 8
  for (int s = 0; s < LCH; ++s) {
    float f = (float)F[base + (int64_t)s * Dd];
    float v = (float)V[base + (int64_t)s * Dd];
    h = fmaf(f, h, v);
    Fp *= f;
  }
  int co = (b * CH + c) * Dd + d;
  Fc[co] = Fp;
  Hc[co] = h;
}

__global__ __launch_bounds__(256) void scan2_k(const float* __restrict__ Fc,
                                               const float* __restrict__ Hc,
                                               float* __restrict__ Carry) {
  int idx = blockIdx.x * 256 + threadIdx.x;  // 0..4095
  int b = idx >> 10, d = idx & (Dd - 1);
  float carry = 0.f;
#pragma unroll
  for (int c = 0; c < CH; ++c) {
    int co = (b * CH + c) * Dd + d;
    Carry[co] = carry;
    carry = fmaf(Fc[co], carry, Hc[co]);
  }
}

__global__ __launch_bounds__(256) void scan3_k(const _Float16* __restrict__ F,
                                               const _Float16* __restrict__ V,
                                               const float* __restrict__ Carry,
                                               float* __restrict__ Out) {
  int d = blockIdx.x * 256 + threadIdx.x;
  int c = blockIdx.y, b = blockIdx.z;
  int64_t base = ((int64_t)b * Ss + c * LCH) * Dd + d;
  float h = Carry[(b * CH + c) * Dd + d];
#pragma unroll 8
  for (int s = 0; s < LCH; ++s) {
    float f = (float)F[base + (int64_t)s * Dd];
    float v = (float)V[base + (int64_t)s * Dd];
    h = fmaf(f, h, v);
    Out[base + (int64_t)s * Dd] = h;
  }
}

// ---------------------------------------------------------------- launch
extern "C" void kernel_launch(void* const* d_in, const int* in_sizes, int n_in,
                              void* d_out, int out_size, void* d_ws, size_t ws_size,
                              hipStream_t stream) {
  const float* x = (const float*)d_in[0];   // [B,S,D] fp32
  const float* W = (const float*)d_in[1];   // [D,3D] fp32
  float* out = (float*)d_out;               // [B,S,D] fp32

  char* ws = (char*)d_ws;
  size_t off = 0;
  auto alloc = [&](size_t bytes) {
    char* p = ws + off;
    off += (bytes + 255) & ~size_t(255);
    return p;
  };
  _Float16* x16    = (_Float16*)alloc((size_t)Mdim * Kdim * 2);       // 32 MiB
  _Float16* w16t   = (_Float16*)alloc((size_t)Ndim * Kdim * 2);       // 6 MiB
  _Float16* gates  = (_Float16*)alloc((size_t)Mdim * Ndim * 2);       // 96 MiB
  _Float16* f16    = (_Float16*)alloc((size_t)Mdim * Dd * 2);         // 32 MiB
  _Float16* v16    = (_Float16*)alloc((size_t)Mdim * Dd * 2);         // 32 MiB
  float* Fc        = (float*)alloc((size_t)Bb * CH * Dd * 4);
  float* Hc        = (float*)alloc((size_t)Bb * CH * Dd * 4);
  float* Carry     = (float*)alloc((size_t)Bb * CH * Dd * 4);
  if (off > ws_size) return;  // workspace too small: fail cleanly

  cvt_x_k<<<2048, 256, 0, stream>>>(x, x16, Mdim * Kdim / 4);
  cvt_wT_k<<<dim3(Ndim / 32, Kdim / 32), 256, 0, stream>>>(W, w16t);
  gemm_f16_k<<<dim3(Ndim / BN, Mdim / BM), 256, 0, stream>>>(x16, w16t, gates);
  combine_k<<<2048, 256, 0, stream>>>(gates, f16, v16);
  scan1_k<<<dim3(Dd / 256, CH, Bb), 256, 0, stream>>>(f16, v16, Fc, Hc);
  scan2_k<<<(Bb * Dd) / 256, 256, 0, stream>>>(Fc, Hc, Carry);
  scan3_k<<<dim3(Dd / 256, CH, Bb), 256, 0, stream>>>(f16, v16, Carry, out);
}

// Round 2
// 227.082 us; speedup vs baseline: 1.7608x; 1.7608x over previous
//
#include <hip/hip_runtime.h>
#include <hip/hip_fp16.h>
#include <cstdint>

typedef _Float16 half8  __attribute__((ext_vector_type(8)));
typedef _Float16 half4v __attribute__((ext_vector_type(4)));
typedef _Float16 half2v __attribute__((ext_vector_type(2)));
typedef float    floatx4 __attribute__((ext_vector_type(4)));

// problem dims (fixed by setup_inputs)
constexpr int Bb = 4, Ss = 4096, Dd = 1024;
constexpr int Mdim = Bb * Ss;          // 16384
constexpr int Ndim = 3 * Dd;           // 3072
constexpr int Kdim = Dd;               // 1024
constexpr int CH = 64, LCH = Ss / CH;  // 64 chunks of 64

// ---------------------------------------------------------------- utils
__device__ __forceinline__ void gload_lds16(const void* g, void* l) {
  __builtin_amdgcn_global_load_lds(
      (const __attribute__((address_space(1))) uint32_t*)g,
      (__attribute__((address_space(3))) uint32_t*)l, 16, 0, 0);
}

// gate math: fw = sig(f)/(sig(f)+sig(i)) = (1+e^-i)/(2+e^-f+e^-i)
//            iw = (1+e^-f)/(2+e^-f+e^-i);  v = iw * g~(h)
__device__ __forceinline__ void gate_fv(float fg, float ig, float hg,
                                        float& fw, float& v) {
  float ef = __expf(fminf(-fg, 40.f));
  float ei = __expf(fminf(-ig, 40.f));
  float r  = __builtin_amdgcn_rcpf(2.f + ef + ei);
  fw = (1.f + ei) * r;
  float iw = (1.f + ef) * r;
  float g  = hg >= 0.f ? hg + 0.5f
                       : __builtin_amdgcn_rcpf(1.f + __expf(fminf(-hg, 40.f)));
  v = iw * g;
}

// ---------------------------------------------------------------- K0a: x fp32 -> fp16
__global__ __launch_bounds__(256) void cvt_x_k(const float* __restrict__ X,
                                               _Float16* __restrict__ X16, int n4) {
  for (int i = blockIdx.x * blockDim.x + threadIdx.x; i < n4;
       i += gridDim.x * blockDim.x) {
    float4 v = ((const float4*)X)[i];
    half4v o = {(_Float16)v.x, (_Float16)v.y, (_Float16)v.z, (_Float16)v.w};
    ((half4v*)X16)[i] = o;
  }
}

// ---------------------------------------------------------------- K0b: W [K][N] fp32 -> WT [N][K] fp16
__global__ __launch_bounds__(256) void cvt_wT_k(const float* __restrict__ W,
                                                _Float16* __restrict__ WT) {
  __shared__ float tile[32][33];
  int tx = threadIdx.x & 31, ty = threadIdx.x >> 5;  // 32 x 8
  int n0 = blockIdx.x * 32, k0 = blockIdx.y * 32;
#pragma unroll
  for (int j = 0; j < 4; ++j) {
    int k = ty + j * 8;
    tile[k][tx] = W[(int64_t)(k0 + k) * Ndim + n0 + tx];
  }
  __syncthreads();
#pragma unroll
  for (int j = 0; j < 4; ++j) {
    int nl = ty + j * 8;
    WT[(int64_t)(n0 + nl) * Kdim + k0 + tx] = (_Float16)tile[tx][nl];
  }
}

// ---------------------------------------------------------------- K1: GEMM (m97 structure)
// A: x16 [M][K] fp16 row-major; BT: W16T [N][K] fp16 row-major; C: gates16 [M][N] fp16
constexpr int BM = 128, BN = 128, BK = 32;

__global__ __launch_bounds__(256, 3) void gemm_f16_k(const _Float16* __restrict__ A,
                                                     const _Float16* __restrict__ BT,
                                                     _Float16* __restrict__ Cg) {
  __shared__ _Float16 As[BM * BK];
  __shared__ _Float16 Bs[BN * BK];
  const int tid = threadIdx.x;
  const int wave = tid >> 6, lane = tid & 63;
  const int m0 = blockIdx.y * BM, n0 = blockIdx.x * BN;
  const int wm = wave >> 1, wn = wave & 1;
  const int l15 = lane & 15, lq = lane >> 4;
  const int k8 = lq * 8;

  // staging: chunk q = r*4 + wave; half base = q*512 + lane*8 (HW: base + lane*16B)
  int aIdx[2], bIdx[2], ldsOff[2];
#pragma unroll
  for (int r = 0; r < 2; ++r) {
    int q = r * 4 + wave;
    int idx = q * 512 + lane * 8;
    int row = idx >> 5, col = idx & 31;
    ldsOff[r] = q * 512;  // wave-uniform
    aIdx[r] = (m0 + row) * Kdim + col;
    bIdx[r] = (n0 + row) * Kdim + col;
  }

  // fragment LDS half-offsets
  int aoff[4], boff[4];
#pragma unroll
  for (int f = 0; f < 4; ++f) {
    aoff[f] = (wm * 64 + f * 16 + l15) * BK + k8;
    boff[f] = (wn * 64 + f * 16 + l15) * BK + k8;
  }

  floatx4 acc[4][4] = {};

  for (int kt = 0; kt < Kdim; kt += BK) {
#pragma unroll
    for (int r = 0; r < 2; ++r) {
      gload_lds16(A + aIdx[r] + kt, (void*)(As + ldsOff[r]));
      gload_lds16(BT + bIdx[r] + kt, (void*)(Bs + ldsOff[r]));
    }
    asm volatile("s_waitcnt vmcnt(0)" ::: "memory");
    __syncthreads();

    half8 bfrag[4];
#pragma unroll
    for (int f = 0; f < 4; ++f) bfrag[f] = *(const half8*)(Bs + boff[f]);
#pragma unroll
    for (int fm = 0; fm < 4; ++fm) {
      half8 afrag = *(const half8*)(As + aoff[fm]);
#pragma unroll
      for (int fn = 0; fn < 4; ++fn)
        acc[fm][fn] = __builtin_amdgcn_mfma_f32_16x16x32_f16(afrag, bfrag[fn],
                                                             acc[fm][fn], 0, 0, 0);
    }
    __syncthreads();
  }

  // epilogue: C/D layout col=lane&15, row=(lane>>4)*4+reg
#pragma unroll
  for (int fm = 0; fm < 4; ++fm) {
    int mrow = m0 + wm * 64 + fm * 16 + lq * 4;
#pragma unroll
    for (int fn = 0; fn < 4; ++fn) {
      int ncol = n0 + wn * 64 + fn * 16 + l15;
#pragma unroll
      for (int r = 0; r < 4; ++r)
        Cg[(int64_t)(mrow + r) * Ndim + ncol] = (_Float16)acc[fm][fn][r];
    }
  }
}

// ---------------------------------------------------------------- K3: per-chunk scan (recomputes gates inline)
// G: gates [M][3D] fp16.  Each thread: 2 adjacent d channels (half2 loads).
__global__ __launch_bounds__(256) void scan1_k(const _Float16* __restrict__ G,
                                               float* __restrict__ Fc,
                                               float* __restrict__ Hc) {
  int d = (blockIdx.x * blockDim.x + threadIdx.x) * 2;  // 0..1022
  int c = blockIdx.y, b = blockIdx.z;
  const _Float16* g = G + (int64_t)(b * Ss + c * LCH) * Ndim + d;
  float h0 = 0.f, h1 = 0.f, F0 = 1.f, F1 = 1.f;
  for (int s = 0; s < LCH; ++s) {
    half2v fg = *(const half2v*)(g);
    half2v ig = *(const half2v*)(g + Dd);
    half2v hg = *(const half2v*)(g + 2 * Dd);
    float fw, v;
    gate_fv((float)fg[0], (float)ig[0], (float)hg[0], fw, v);
    h0 = fmaf(fw, h0, v);
    F0 *= fw;
    gate_fv((float)fg[1], (float)ig[1], (float)hg[1], fw, v);
    h1 = fmaf(fw, h1, v);
    F1 *= fw;
    g += Ndim;
  }
  int co = (b * CH + c) * Dd + d;
  *(float2*)(Fc + co) = make_float2(F0, F1);
  *(float2*)(Hc + co) = make_float2(h0, h1);
}

// ---------------------------------------------------------------- K4: chunk-carry scan (tiny)
__global__ __launch_bounds__(256) void scan2_k(const float* __restrict__ Fc,
                                               const float* __restrict__ Hc,
                                               float* __restrict__ Carry) {
  int idx = blockIdx.x * 256 + threadIdx.x;  // 0..4095
  int b = idx >> 10, d = idx & (Dd - 1);
  float carry = 0.f;
#pragma unroll
  for (int c = 0; c < CH; ++c) {
    int co = (b * CH + c) * Dd + d;
    Carry[co] = carry;
    carry = fmaf(Fc[co], carry, Hc[co]);
  }
}

// ---------------------------------------------------------------- K5: replay with carry, write fp32 out
__global__ __launch_bounds__(256) void scan3_k(const _Float16* __restrict__ G,
                                               const float* __restrict__ Carry,
                                               float* __restrict__ Out) {
  int d = (blockIdx.x * blockDim.x + threadIdx.x) * 2;
  int c = blockIdx.y, b = blockIdx.z;
  int64_t row0 = (int64_t)(b * Ss + c * LCH);
  const _Float16* g = G + row0 * Ndim + d;
  float* o = Out + row0 * Dd + d;
  int co = (b * CH + c) * Dd + d;
  float h0 = Carry[co], h1 = Carry[co + 1];
  for (int s = 0; s < LCH; ++s) {
    half2v fg = *(const half2v*)(g);
    half2v ig = *(const half2v*)(g + Dd);
    half2v hg = *(const half2v*)(g + 2 * Dd);
    float fw, v;
    gate_fv((float)fg[0], (float)ig[0], (float)hg[0], fw, v);
    h0 = fmaf(fw, h0, v);
    gate_fv((float)fg[1], (float)ig[1], (float)hg[1], fw, v);
    h1 = fmaf(fw, h1, v);
    *(float2*)o = make_float2(h0, h1);
    g += Ndim;
    o += Dd;
  }
}

// ---------------------------------------------------------------- launch
extern "C" void kernel_launch(void* const* d_in, const int* in_sizes, int n_in,
                              void* d_out, int out_size, void* d_ws, size_t ws_size,
                              hipStream_t stream) {
  const float* x = (const float*)d_in[0];   // [B,S,D] fp32
  const float* W = (const float*)d_in[1];   // [D,3D] fp32
  float* out = (float*)d_out;               // [B,S,D] fp32

  char* ws = (char*)d_ws;
  size_t off = 0;
  auto alloc = [&](size_t bytes) {
    char* p = ws + off;
    off += (bytes + 255) & ~size_t(255);
    return p;
  };
  _Float16* x16    = (_Float16*)alloc((size_t)Mdim * Kdim * 2);       // 32 MiB
  _Float16* w16t   = (_Float16*)alloc((size_t)Ndim * Kdim * 2);       // 6 MiB
  _Float16* gates  = (_Float16*)alloc((size_t)Mdim * Ndim * 2);       // 96 MiB
  float* Fc        = (float*)alloc((size_t)Bb * CH * Dd * 4);         // 1 MiB
  float* Hc        = (float*)alloc((size_t)Bb * CH * Dd * 4);
  float* Carry     = (float*)alloc((size_t)Bb * CH * Dd * 4);
  if (off > ws_size) return;  // workspace too small: fail cleanly

  cvt_x_k<<<2048, 256, 0, stream>>>(x, x16, Mdim * Kdim / 4);
  cvt_wT_k<<<dim3(Ndim / 32, Kdim / 32), 256, 0, stream>>>(W, w16t);
  gemm_f16_k<<<dim3(Ndim / BN, Mdim / BM), 256, 0, stream>>>(x16, w16t, gates);
  scan1_k<<<dim3(Dd / 512, CH, Bb), 256, 0, stream>>>(gates, Fc, Hc);
  scan2_k<<<(Bb * Dd) / 256, 256, 0, stream>>>(Fc, Hc, Carry);
  scan3_k<<<dim3(Dd / 512, CH, Bb), 256, 0, stream>>>(gates, Carry, out);
}

// Round 3
// 204.606 us; speedup vs baseline: 1.9542x; 1.1098x over previous
//
#include <hip/hip_runtime.h>
#include <hip/hip_fp16.h>
#include <cstdint>

typedef _Float16 half8  __attribute__((ext_vector_type(8)));
typedef _Float16 half4v __attribute__((ext_vector_type(4)));
typedef _Float16 half2v __attribute__((ext_vector_type(2)));
typedef float    floatx4 __attribute__((ext_vector_type(4)));

// problem dims (fixed by setup_inputs)
constexpr int Bb = 4, Ss = 4096, Dd = 1024;
constexpr int Mdim = Bb * Ss;          // 16384
constexpr int Ndim = 3 * Dd;           // 3072
constexpr int Kdim = Dd;               // 1024
constexpr int CH = 64, LCH = Ss / CH;  // 64 chunks of 64

// ---------------------------------------------------------------- utils
__device__ __forceinline__ void gload_lds16(const void* g, void* l) {
  __builtin_amdgcn_global_load_lds(
      (const __attribute__((address_space(1))) uint32_t*)g,
      (__attribute__((address_space(3))) uint32_t*)l, 16, 0, 0);
}

// gate math: fw = sig(f)/(sig(f)+sig(i)) = (1+e^-i)/(2+e^-f+e^-i)
//            iw = (1+e^-f)/(2+e^-f+e^-i);  v = iw * g~(h)
__device__ __forceinline__ void gate_fv(float fg, float ig, float hg,
                                        float& fw, float& v) {
  float ef = __expf(fminf(-fg, 40.f));
  float ei = __expf(fminf(-ig, 40.f));
  float r  = __builtin_amdgcn_rcpf(2.f + ef + ei);
  fw = (1.f + ei) * r;
  float iw = (1.f + ef) * r;
  float g  = hg >= 0.f ? hg + 0.5f
                       : __builtin_amdgcn_rcpf(1.f + __expf(fminf(-hg, 40.f)));
  v = iw * g;
}

// ---------------------------------------------------------------- K0a: x fp32 -> fp16
__global__ __launch_bounds__(256) void cvt_x_k(const float* __restrict__ X,
                                               _Float16* __restrict__ X16, int n4) {
  for (int i = blockIdx.x * blockDim.x + threadIdx.x; i < n4;
       i += gridDim.x * blockDim.x) {
    float4 v = ((const float4*)X)[i];
    half4v o = {(_Float16)v.x, (_Float16)v.y, (_Float16)v.z, (_Float16)v.w};
    ((half4v*)X16)[i] = o;
  }
}

// ---------------------------------------------------------------- K0b: W [K][N] fp32 -> WT [N][K] fp16
__global__ __launch_bounds__(256) void cvt_wT_k(const float* __restrict__ W,
                                                _Float16* __restrict__ WT) {
  __shared__ float tile[32][33];
  int tx = threadIdx.x & 31, ty = threadIdx.x >> 5;  // 32 x 8
  int n0 = blockIdx.x * 32, k0 = blockIdx.y * 32;
#pragma unroll
  for (int j = 0; j < 4; ++j) {
    int k = ty + j * 8;
    tile[k][tx] = W[(int64_t)(k0 + k) * Ndim + n0 + tx];
  }
  __syncthreads();
#pragma unroll
  for (int j = 0; j < 4; ++j) {
    int nl = ty + j * 8;
    WT[(int64_t)(n0 + nl) * Kdim + k0 + tx] = (_Float16)tile[tx][nl];
  }
}

// ---------------------------------------------------------------- K1: 256x256 8-phase GEMM
// A: x16 [M][K]; BT: W16T [N][K]; C: gates16 [M][N]. All fp16.
// LDS layout per buffer (64 KiB): A-half0 | A-half1 | B-half0 | B-half1, each
// 128 rows x 64 cols fp16 = 16 KiB, row stride 128 B, XOR-swizzled 16B slots:
// slot q of row r holds global col-block (q ^ (r&7)).
constexpr int GBM = 256, GBN = 256, GBK = 64;
constexpr int NT = Kdim / GBK;  // 16 K-tiles

__global__ __launch_bounds__(512, 2) void gemm8_k(const _Float16* __restrict__ A,
                                                  const _Float16* __restrict__ BT,
                                                  _Float16* __restrict__ Cg) {
  extern __shared__ char lds[];  // 131072 bytes
  const int tid = threadIdx.x;
  const int wid = tid >> 6, lane = tid & 63;
  const int wm = wid >> 2, wn = wid & 3;
  const int l15 = lane & 15, lq = lane >> 4;

  // XCD-aware swizzle (768 % 8 == 0 -> simple variant is bijective)
  int wg = blockIdx.x;
  wg = (wg & 7) * 96 + (wg >> 3);
  const int n0 = (wg % 12) * GBN;
  const int m0 = (wg / 12) * GBM;

  // LDS read byte-offsets within a half (swizzled)
  int aOff[4][2], bOff[2][2];
#pragma unroll
  for (int mi = 0; mi < 4; ++mi)
#pragma unroll
    for (int ks = 0; ks < 2; ++ks) {
      int r = wm * 64 + mi * 16 + l15;
      aOff[mi][ks] = r * 128 + ((((ks << 2) + lq) ^ (r & 7)) << 4);
    }
#pragma unroll
  for (int ni = 0; ni < 2; ++ni)
#pragma unroll
    for (int ks = 0; ks < 2; ++ks) {
      int r = wn * 32 + ni * 16 + l15;
      bOff[ni][ks] = r * 128 + ((((ks << 2) + lq) ^ (r & 7)) << 4);
    }

  // staging geometry: thread -> (row srr + 64*round, slot ss); dest linear,
  // source column pre-inverse-swizzled (rule #21)
  const int srr = (wid << 3) + (lane >> 3);
  const int ss = lane & 7;
  const _Float16* Abase = A + (size_t)m0 * Kdim;
  const _Float16* Bbase = BT + (size_t)n0 * Kdim;

  auto stage = [&](const _Float16* gsrc, int ldsHalfBase) {
#pragma unroll
    for (int round = 0; round < 2; ++round) {
      int r = (round << 6) + srr;
      int c = ss ^ (r & 7);
      gload_lds16(gsrc + (size_t)r * Kdim + (c << 3),
                  lds + ldsHalfBase + (round << 13) + (wid << 10));
    }
  };

  floatx4 acc[8][4] = {};
  half8 afrag[4][2], bfrag[2][2];

  // prologue: tile0 all 4 halves + tile1 A0,B0  (12 loads/wave-lane)
  stage(Abase, 0);                          // A0(0)
  stage(Bbase, 32768);                      // B0(0)
  stage(Bbase + 128 * Kdim, 49152);         // B1(0)
  stage(Abase + 128 * Kdim, 16384);         // A1(0)
  stage(Abase + 64, 65536);                 // A0(1)
  stage(Bbase + 64, 65536 + 32768);         // B0(1)
  asm volatile("s_waitcnt vmcnt(4)" ::: "memory");  // tile0 fully landed
  __builtin_amdgcn_s_barrier();

  for (int kt = 0; kt < NT; ++kt) {
    const int cur = (kt & 1) << 16, nxt = ((kt + 1) & 1) << 16;
    const _Float16* Akt1 = Abase + (kt + 1) * GBK;
    const _Float16* Bkt1 = Bbase + (kt + 1) * GBK;
    const _Float16* Akt2 = Abase + (kt + 2) * GBK;
    const _Float16* Bkt2 = Bbase + (kt + 2) * GBK;

    // ---- phase 0: quadrant (A0,B0); reads A-half0(8) + B-half0(4)
#pragma unroll
    for (int mi = 0; mi < 4; ++mi)
#pragma unroll
      for (int ks = 0; ks < 2; ++ks)
        afrag[mi][ks] = *(const half8*)(lds + cur + aOff[mi][ks]);
#pragma unroll
    for (int ni = 0; ni < 2; ++ni)
#pragma unroll
      for (int ks = 0; ks < 2; ++ks)
        bfrag[ni][ks] = *(const half8*)(lds + cur + 32768 + bOff[ni][ks]);
    if (kt + 1 < NT) stage(Bkt1 + 128 * Kdim, nxt + 49152);  // B1(kt+1)
    __builtin_amdgcn_s_barrier();
    asm volatile("s_waitcnt lgkmcnt(0)" ::: "memory");
    __builtin_amdgcn_sched_barrier(0);
    __builtin_amdgcn_s_setprio(1);
#pragma unroll
    for (int ks = 0; ks < 2; ++ks)
#pragma unroll
      for (int mi = 0; mi < 4; ++mi)
#pragma unroll
        for (int ni = 0; ni < 2; ++ni)
          acc[mi][ni] = __builtin_amdgcn_mfma_f32_16x16x32_f16(
              afrag[mi][ks], bfrag[ni][ks], acc[mi][ni], 0, 0, 0);
    __builtin_amdgcn_s_setprio(0);
    __builtin_amdgcn_s_barrier();

    // ---- phase 1: quadrant (A0,B1); reads B-half1(4), A kept in regs
#pragma unroll
    for (int ni = 0; ni < 2; ++ni)
#pragma unroll
      for (int ks = 0; ks < 2; ++ks)
        bfrag[ni][ks] = *(const half8*)(lds + cur + 49152 + bOff[ni][ks]);
    if (kt + 1 < NT) stage(Akt1 + 128 * Kdim, nxt + 16384);  // A1(kt+1)
    __builtin_amdgcn_s_barrier();
    asm volatile("s_waitcnt lgkmcnt(0)" ::: "memory");
    __builtin_amdgcn_sched_barrier(0);
    __builtin_amdgcn_s_setprio(1);
#pragma unroll
    for (int ks = 0; ks < 2; ++ks)
#pragma unroll
      for (int mi = 0; mi < 4; ++mi)
#pragma unroll
        for (int ni = 0; ni < 2; ++ni)
          acc[mi][2 + ni] = __builtin_amdgcn_mfma_f32_16x16x32_f16(
              afrag[mi][ks], bfrag[ni][ks], acc[mi][2 + ni], 0, 0, 0);
    __builtin_amdgcn_s_setprio(0);
    __builtin_amdgcn_s_barrier();

    // ---- phase 2: quadrant (A1,B0); reads A-half1(8) + B-half0(4)
#pragma unroll
    for (int mi = 0; mi < 4; ++mi)
#pragma unroll
      for (int ks = 0; ks < 2; ++ks)
        afrag[mi][ks] = *(const half8*)(lds + cur + 16384 + aOff[mi][ks]);
#pragma unroll
    for (int ni = 0; ni < 2; ++ni)
#pragma unroll
      for (int ks = 0; ks < 2; ++ks)
        bfrag[ni][ks] = *(const half8*)(lds + cur + 32768 + bOff[ni][ks]);
    if (kt + 2 < NT) stage(Akt2, cur + 0);  // A0(kt+2): A0-cur dead after ph1
    __builtin_amdgcn_s_barrier();
    asm volatile("s_waitcnt lgkmcnt(0)" ::: "memory");
    __builtin_amdgcn_sched_barrier(0);
    __builtin_amdgcn_s_setprio(1);
#pragma unroll
    for (int ks = 0; ks < 2; ++ks)
#pragma unroll
      for (int mi = 0; mi < 4; ++mi)
#pragma unroll
        for (int ni = 0; ni < 2; ++ni)
          acc[4 + mi][ni] = __builtin_amdgcn_mfma_f32_16x16x32_f16(
              afrag[mi][ks], bfrag[ni][ks], acc[4 + mi][ni], 0, 0, 0);
    __builtin_amdgcn_s_setprio(0);
    __builtin_amdgcn_s_barrier();

    // ---- phase 3: quadrant (A1,B1); reads B-half1(4)
#pragma unroll
    for (int ni = 0; ni < 2; ++ni)
#pragma unroll
      for (int ks = 0; ks < 2; ++ks)
        bfrag[ni][ks] = *(const half8*)(lds + cur + 49152 + bOff[ni][ks]);
    if (kt + 2 < NT) stage(Bkt2, cur + 32768);  // B0(kt+2): B0-cur dead after ph2
    __builtin_amdgcn_s_barrier();
    asm volatile("s_waitcnt lgkmcnt(0)" ::: "memory");
    __builtin_amdgcn_sched_barrier(0);
    __builtin_amdgcn_s_setprio(1);
#pragma unroll
    for (int ks = 0; ks < 2; ++ks)
#pragma unroll
      for (int mi = 0; mi < 4; ++mi)
#pragma unroll
        for (int ni = 0; ni < 2; ++ni)
          acc[4 + mi][2 + ni] = __builtin_amdgcn_mfma_f32_16x16x32_f16(
              afrag[mi][ks], bfrag[ni][ks], acc[4 + mi][2 + ni], 0, 0, 0);
    __builtin_amdgcn_s_setprio(0);

    // K-tile boundary: counted vmcnt (never 0 mid-loop), then barrier
    if (kt < NT - 2) {
      asm volatile("s_waitcnt vmcnt(4)" ::: "memory");
      __builtin_amdgcn_s_barrier();
    } else if (kt == NT - 2) {
      asm volatile("s_waitcnt vmcnt(0)" ::: "memory");  // drain: no stages left
      __builtin_amdgcn_s_barrier();
    }
  }

  // epilogue: D layout col=l15, row=lq*4+r
#pragma unroll
  for (int mf = 0; mf < 8; ++mf) {
    int row = m0 + ((mf >> 2) << 7) + wm * 64 + ((mf & 3) << 4) + (lq << 2);
#pragma unroll
    for (int nf = 0; nf < 4; ++nf) {
      int col = n0 + ((nf >> 1) << 7) + wn * 32 + ((nf & 1) << 4) + l15;
#pragma unroll
      for (int r = 0; r < 4; ++r)
        Cg[(size_t)(row + r) * Ndim + col] = (_Float16)acc[mf][nf][r];
    }
  }
}

// ---------------------------------------------------------------- K3: per-chunk scan (recomputes gates inline)
__global__ __launch_bounds__(256) void scan1_k(const _Float16* __restrict__ G,
                                               float* __restrict__ Fc,
                                               float* __restrict__ Hc) {
  int d = (blockIdx.x * blockDim.x + threadIdx.x) * 2;  // 0..1022
  int c = blockIdx.y, b = blockIdx.z;
  const _Float16* g = G + (int64_t)(b * Ss + c * LCH) * Ndim + d;
  float h0 = 0.f, h1 = 0.f, F0 = 1.f, F1 = 1.f;
  for (int s = 0; s < LCH; ++s) {
    half2v fg = *(const half2v*)(g);
    half2v ig = *(const half2v*)(g + Dd);
    half2v hg = *(const half2v*)(g + 2 * Dd);
    float fw, v;
    gate_fv((float)fg[0], (float)ig[0], (float)hg[0], fw, v);
    h0 = fmaf(fw, h0, v);
    F0 *= fw;
    gate_fv((float)fg[1], (float)ig[1], (float)hg[1], fw, v);
    h1 = fmaf(fw, h1, v);
    F1 *= fw;
    g += Ndim;
  }
  int co = (b * CH + c) * Dd + d;
  *(float2*)(Fc + co) = make_float2(F0, F1);
  *(float2*)(Hc + co) = make_float2(h0, h1);
}

// ---------------------------------------------------------------- K4: chunk-carry scan (tiny)
__global__ __launch_bounds__(256) void scan2_k(const float* __restrict__ Fc,
                                               const float* __restrict__ Hc,
                                               float* __restrict__ Carry) {
  int idx = blockIdx.x * 256 + threadIdx.x;  // 0..4095
  int b = idx >> 10, d = idx & (Dd - 1);
  float carry = 0.f;
#pragma unroll
  for (int c = 0; c < CH; ++c) {
    int co = (b * CH + c) * Dd + d;
    Carry[co] = carry;
    carry = fmaf(Fc[co], carry, Hc[co]);
  }
}

// ---------------------------------------------------------------- K5: replay with carry, write fp32 out
__global__ __launch_bounds__(256) void scan3_k(const _Float16* __restrict__ G,
                                               const float* __restrict__ Carry,
                                               float* __restrict__ Out) {
  int d = (blockIdx.x * blockDim.x + threadIdx.x) * 2;
  int c = blockIdx.y, b = blockIdx.z;
  int64_t row0 = (int64_t)(b * Ss + c * LCH);
  const _Float16* g = G + row0 * Ndim + d;
  float* o = Out + row0 * Dd + d;
  int co = (b * CH + c) * Dd + d;
  float h0 = Carry[co], h1 = Carry[co + 1];
  for (int s = 0; s < LCH; ++s) {
    half2v fg = *(const half2v*)(g);
    half2v ig = *(const half2v*)(g + Dd);
    half2v hg = *(const half2v*)(g + 2 * Dd);
    float fw, v;
    gate_fv((float)fg[0], (float)ig[0], (float)hg[0], fw, v);
    h0 = fmaf(fw, h0, v);
    gate_fv((float)fg[1], (float)ig[1], (float)hg[1], fw, v);
    h1 = fmaf(fw, h1, v);
    *(float2*)o = make_float2(h0, h1);
    g += Ndim;
    o += Dd;
  }
}

// ---------------------------------------------------------------- launch
extern "C" void kernel_launch(void* const* d_in, const int* in_sizes, int n_in,
                              void* d_out, int out_size, void* d_ws, size_t ws_size,
                              hipStream_t stream) {
  const float* x = (const float*)d_in[0];   // [B,S,D] fp32
  const float* W = (const float*)d_in[1];   // [D,3D] fp32
  float* out = (float*)d_out;               // [B,S,D] fp32

  char* ws = (char*)d_ws;
  size_t off = 0;
  auto alloc = [&](size_t bytes) {
    char* p = ws + off;
    off += (bytes + 255) & ~size_t(255);
    return p;
  };
  _Float16* x16    = (_Float16*)alloc((size_t)Mdim * Kdim * 2);       // 32 MiB
  _Float16* w16t   = (_Float16*)alloc((size_t)Ndim * Kdim * 2);       // 6 MiB
  _Float16* gates  = (_Float16*)alloc((size_t)Mdim * Ndim * 2);       // 96 MiB
  float* Fc        = (float*)alloc((size_t)Bb * CH * Dd * 4);         // 1 MiB
  float* Hc        = (float*)alloc((size_t)Bb * CH * Dd * 4);
  float* Carry     = (float*)alloc((size_t)Bb * CH * Dd * 4);
  if (off > ws_size) return;  // workspace too small: fail cleanly

  cvt_x_k<<<2048, 256, 0, stream>>>(x, x16, Mdim * Kdim / 4);
  cvt_wT_k<<<dim3(Ndim / 32, Kdim / 32), 256, 0, stream>>>(W, w16t);
  gemm8_k<<<dim3((Mdim / GBM) * (Ndim / GBN)), 512, 131072, stream>>>(x16, w16t, gates);
  scan1_k<<<dim3(Dd / 512, CH, Bb), 256, 0, stream>>>(gates, Fc, Hc);
  scan2_k<<<(Bb * Dd) / 256, 256, 0, stream>>>(Fc, Hc, Carry);
  scan3_k<<<dim3(Dd / 512, CH, Bb), 256, 0, stream>>>(gates, Carry, out);
}

// Round 4
// 200.742 us; speedup vs baseline: 1.9918x; 1.0193x over previous
//
#include <hip/hip_runtime.h>
#include <hip/hip_fp16.h>
#include <cstdint>

typedef _Float16 half8  __attribute__((ext_vector_type(8)));
typedef _Float16 half4v __attribute__((ext_vector_type(4)));
typedef _Float16 half2v __attribute__((ext_vector_type(2)));
typedef float    floatx4 __attribute__((ext_vector_type(4)));

// problem dims (fixed by setup_inputs)
constexpr int Bb = 4, Ss = 4096, Dd = 1024;
constexpr int Mdim = Bb * Ss;          // 16384
constexpr int Ndim = 3 * Dd;           // 3072
constexpr int Kdim = Dd;               // 1024
constexpr int CH = 64, LCH = Ss / CH;  // 64 chunks of 64

// ---------------------------------------------------------------- utils
__device__ __forceinline__ void gload_lds16(const void* g, void* l) {
  __builtin_amdgcn_global_load_lds(
      (const __attribute__((address_space(1))) uint32_t*)g,
      (__attribute__((address_space(3))) uint32_t*)l, 16, 0, 0);
}

// gate math: fw = sig(f)/(sig(f)+sig(i)) = (1+e^-i)/(2+e^-f+e^-i)
//            iw = (1+e^-f)/(2+e^-f+e^-i);  v = iw * g~(h)
__device__ __forceinline__ void gate_fv(float fg, float ig, float hg,
                                        float& fw, float& v) {
  float ef = __expf(fminf(-fg, 40.f));
  float ei = __expf(fminf(-ig, 40.f));
  float r  = __builtin_amdgcn_rcpf(2.f + ef + ei);
  fw = (1.f + ei) * r;
  float iw = (1.f + ef) * r;
  float g  = hg >= 0.f ? hg + 0.5f
                       : __builtin_amdgcn_rcpf(1.f + __expf(fminf(-hg, 40.f)));
  v = iw * g;
}

// ---------------------------------------------------------------- K0a: x fp32 -> fp16
__global__ __launch_bounds__(256) void cvt_x_k(const float* __restrict__ X,
                                               _Float16* __restrict__ X16, int n4) {
  for (int i = blockIdx.x * blockDim.x + threadIdx.x; i < n4;
       i += gridDim.x * blockDim.x) {
    float4 v = ((const float4*)X)[i];
    half4v o = {(_Float16)v.x, (_Float16)v.y, (_Float16)v.z, (_Float16)v.w};
    ((half4v*)X16)[i] = o;
  }
}

// ---------------------------------------------------------------- K0b: W [K][N] fp32 -> WT [N][K] fp16
__global__ __launch_bounds__(256) void cvt_wT_k(const float* __restrict__ W,
                                                _Float16* __restrict__ WT) {
  __shared__ float tile[32][33];
  int tx = threadIdx.x & 31, ty = threadIdx.x >> 5;  // 32 x 8
  int n0 = blockIdx.x * 32, k0 = blockIdx.y * 32;
#pragma unroll
  for (int j = 0; j < 4; ++j) {
    int k = ty + j * 8;
    tile[k][tx] = W[(int64_t)(k0 + k) * Ndim + n0 + tx];
  }
  __syncthreads();
#pragma unroll
  for (int j = 0; j < 4; ++j) {
    int nl = ty + j * 8;
    WT[(int64_t)(n0 + nl) * Kdim + k0 + tx] = (_Float16)tile[tx][nl];
  }
}

// ---------------------------------------------------------------- K1: 256x256 GEMM, deep-prefetch 2-barrier/tile
// A: x16 [M][K]; BT: W16T [N][K]; C: gates16 [M][N]. All fp16.
// LDS per buffer (64 KiB): A-half0 | A-half1 | B-half0 | B-half1, each
// 128 rows x 64 cols fp16, row stride 128 B, XOR-swizzled 16B slots:
// slot q of row r holds global col-block (q ^ (r&7)).
constexpr int GBM = 256, GBN = 256, GBK = 64;
constexpr int NT = Kdim / GBK;  // 16 K-tiles

__global__ __launch_bounds__(512, 2) void gemm8_k(const _Float16* __restrict__ A,
                                                  const _Float16* __restrict__ BT,
                                                  _Float16* __restrict__ Cg) {
  extern __shared__ char lds[];  // 131072 bytes
  const int tid = threadIdx.x;
  const int wid = tid >> 6, lane = tid & 63;
  const int wm = wid >> 2, wn = wid & 3;
  const int l15 = lane & 15, lq = lane >> 4;

  // XCD-aware swizzle (768 % 8 == 0 -> simple variant is bijective)
  int wg = blockIdx.x;
  wg = (wg & 7) * 96 + (wg >> 3);
  const int n0 = (wg % 12) * GBN;
  const int m0 = (wg / 12) * GBM;

  // LDS read byte-offsets within a half for ks=0; ks=1 is offset ^ 64
  // (slot(ks=1) = slot(ks=0) ^ 4 under the XOR swizzle).
  int aO[4], bO[2];
#pragma unroll
  for (int mi = 0; mi < 4; ++mi) {
    int r = wm * 64 + mi * 16 + l15;
    aO[mi] = r * 128 + ((lq ^ (r & 7)) << 4);
  }
#pragma unroll
  for (int ni = 0; ni < 2; ++ni) {
    int r = wn * 32 + ni * 16 + l15;
    bO[ni] = r * 128 + ((lq ^ (r & 7)) << 4);
  }

  // staging geometry: thread -> (row srr + 64*round, slot ss); dest linear,
  // source column pre-inverse-swizzled (rule #21)
  const int srr = (wid << 3) + (lane >> 3);
  const int ss = lane & 7;
  const _Float16* Abase = A + (size_t)m0 * Kdim;
  const _Float16* Bbase = BT + (size_t)n0 * Kdim;

  auto stage = [&](const _Float16* gsrc, int ldsHalfBase) {
#pragma unroll
    for (int round = 0; round < 2; ++round) {
      int r = (round << 6) + srr;
      int c = ss ^ (r & 7);
      gload_lds16(gsrc + (size_t)r * Kdim + (c << 3),
                  lds + ldsHalfBase + (round << 13) + (wid << 10));
    }
  };

  floatx4 acc[8][4] = {};

  // prologue: tile0 all 4 halves + tile1 A0,B0  (12 loads/lane-slice)
  stage(Abase, 0);                          // A0(0)
  stage(Bbase, 32768);                      // B0(0)
  stage(Bbase + 128 * Kdim, 49152);         // B1(0)
  stage(Abase + 128 * Kdim, 16384);         // A1(0)
  stage(Abase + 64, 65536);                 // A0(1)
  stage(Bbase + 64, 65536 + 32768);         // B0(1)
  asm volatile("s_waitcnt vmcnt(4)" ::: "memory");  // tile0 fully landed
  __builtin_amdgcn_s_barrier();

  for (int kt = 0; kt < NT; ++kt) {
    const int cur = (kt & 1) << 16, nxt = ((kt + 1) & 1) << 16;
    const _Float16* Akt1 = Abase + (kt + 1) * GBK;
    const _Float16* Bkt1 = Bbase + (kt + 1) * GBK;
    const _Float16* Akt2 = Abase + (kt + 2) * GBK;
    const _Float16* Bkt2 = Bbase + (kt + 2) * GBK;

    half8 a[4][2], b0[2][2], b1[2][2];

    // ---- issue reads: A0(8), B0(4), B1(4) — B halves cached for whole tile
#pragma unroll
    for (int mi = 0; mi < 4; ++mi)
#pragma unroll
      for (int ks = 0; ks < 2; ++ks)
        a[mi][ks] = *(const half8*)(lds + cur + (aO[mi] ^ (ks << 6)));
#pragma unroll
    for (int ni = 0; ni < 2; ++ni)
#pragma unroll
      for (int ks = 0; ks < 2; ++ks) {
        b0[ni][ks] = *(const half8*)(lds + cur + 32768 + (bO[ni] ^ (ks << 6)));
        b1[ni][ks] = *(const half8*)(lds + cur + 49152 + (bO[ni] ^ (ks << 6)));
      }
    if (kt + 1 < NT) stage(Bkt1 + 128 * Kdim, nxt + 49152);  // s0: B1(kt+1)

    // ---- Q0 = A0 x B0
    __builtin_amdgcn_s_setprio(1);
#pragma unroll
    for (int ks = 0; ks < 2; ++ks)
#pragma unroll
      for (int mi = 0; mi < 4; ++mi)
#pragma unroll
        for (int ni = 0; ni < 2; ++ni)
          acc[mi][ni] = __builtin_amdgcn_mfma_f32_16x16x32_f16(
              a[mi][ks], b0[ni][ks], acc[mi][ni], 0, 0, 0);
    __builtin_amdgcn_s_setprio(0);
    if (kt + 1 < NT) stage(Akt1 + 128 * Kdim, nxt + 16384);  // s1: A1(kt+1)

    // ---- Q1 = A0 x B1
    __builtin_amdgcn_s_setprio(1);
#pragma unroll
    for (int ks = 0; ks < 2; ++ks)
#pragma unroll
      for (int mi = 0; mi < 4; ++mi)
#pragma unroll
        for (int ni = 0; ni < 2; ++ni)
          acc[mi][2 + ni] = __builtin_amdgcn_mfma_f32_16x16x32_f16(
              a[mi][ks], b1[ni][ks], acc[mi][2 + ni], 0, 0, 0);
    __builtin_amdgcn_s_setprio(0);

    // mid barrier: all waves' cur A0/B0 reads complete (pre-Q0) before restage
    __builtin_amdgcn_s_barrier();

    // ---- A1 reads (reuse a[] regs; A0 dead after Q1)
#pragma unroll
    for (int mi = 0; mi < 4; ++mi)
#pragma unroll
      for (int ks = 0; ks < 2; ++ks)
        a[mi][ks] = *(const half8*)(lds + cur + 16384 + (aO[mi] ^ (ks << 6)));
    if (kt + 2 < NT) stage(Akt2, cur + 0);  // s2: A0(kt+2) over dead cur-A0

    // ---- Q2 = A1 x B0
    __builtin_amdgcn_s_setprio(1);
#pragma unroll
    for (int ks = 0; ks < 2; ++ks)
#pragma unroll
      for (int mi = 0; mi < 4; ++mi)
#pragma unroll
        for (int ni = 0; ni < 2; ++ni)
          acc[4 + mi][ni] = __builtin_amdgcn_mfma_f32_16x16x32_f16(
              a[mi][ks], b0[ni][ks], acc[4 + mi][ni], 0, 0, 0);
    __builtin_amdgcn_s_setprio(0);
    if (kt + 2 < NT) stage(Bkt2, cur + 32768);  // s3: B0(kt+2) over dead cur-B0

    // ---- Q3 = A1 x B1
    __builtin_amdgcn_s_setprio(1);
#pragma unroll
    for (int ks = 0; ks < 2; ++ks)
#pragma unroll
      for (int mi = 0; mi < 4; ++mi)
#pragma unroll
        for (int ni = 0; ni < 2; ++ni)
          acc[4 + mi][2 + ni] = __builtin_amdgcn_mfma_f32_16x16x32_f16(
              a[mi][ks], b1[ni][ks], acc[4 + mi][2 + ni], 0, 0, 0);
    __builtin_amdgcn_s_setprio(0);

    // K-tile boundary: counted vmcnt (never 0 mid-loop), then barrier
    if (kt < NT - 2) {
      asm volatile("s_waitcnt vmcnt(4)" ::: "memory");
      __builtin_amdgcn_s_barrier();
    } else if (kt == NT - 2) {
      asm volatile("s_waitcnt vmcnt(0)" ::: "memory");  // drain: no stages left
      __builtin_amdgcn_s_barrier();
    }
  }

  // epilogue: D layout col=l15, row=lq*4+r
#pragma unroll
  for (int mf = 0; mf < 8; ++mf) {
    int row = m0 + ((mf >> 2) << 7) + wm * 64 + ((mf & 3) << 4) + (lq << 2);
#pragma unroll
    for (int nf = 0; nf < 4; ++nf) {
      int col = n0 + ((nf >> 1) << 7) + wn * 32 + ((nf & 1) << 4) + l15;
#pragma unroll
      for (int r = 0; r < 4; ++r)
        Cg[(size_t)(row + r) * Ndim + col] = (_Float16)acc[mf][nf][r];
    }
  }
}

// ---------------------------------------------------------------- K3: per-chunk scan (recomputes gates inline)
__global__ __launch_bounds__(256) void scan1_k(const _Float16* __restrict__ G,
                                               float* __restrict__ Fc,
                                               float* __restrict__ Hc) {
  int d = (blockIdx.x * blockDim.x + threadIdx.x) * 2;  // 0..1022
  int c = blockIdx.y, b = blockIdx.z;
  const _Float16* g = G + (int64_t)(b * Ss + c * LCH) * Ndim + d;
  float h0 = 0.f, h1 = 0.f, F0 = 1.f, F1 = 1.f;
  for (int s = 0; s < LCH; ++s) {
    half2v fg = *(const half2v*)(g);
    half2v ig = *(const half2v*)(g + Dd);
    half2v hg = *(const half2v*)(g + 2 * Dd);
    float fw, v;
    gate_fv((float)fg[0], (float)ig[0], (float)hg[0], fw, v);
    h0 = fmaf(fw, h0, v);
    F0 *= fw;
    gate_fv((float)fg[1], (float)ig[1], (float)hg[1], fw, v);
    h1 = fmaf(fw, h1, v);
    F1 *= fw;
    g += Ndim;
  }
  int co = (b * CH + c) * Dd + d;
  *(float2*)(Fc + co) = make_float2(F0, F1);
  *(float2*)(Hc + co) = make_float2(h0, h1);
}

// ---------------------------------------------------------------- K4: chunk-carry scan (tiny)
__global__ __launch_bounds__(256) void scan2_k(const float* __restrict__ Fc,
                                               const float* __restrict__ Hc,
                                               float* __restrict__ Carry) {
  int idx = blockIdx.x * 256 + threadIdx.x;  // 0..4095
  int b = idx >> 10, d = idx & (Dd - 1);
  float carry = 0.f;
#pragma unroll
  for (int c = 0; c < CH; ++c) {
    int co = (b * CH + c) * Dd + d;
    Carry[co] = carry;
    carry = fmaf(Fc[co], carry, Hc[co]);
  }
}

// ---------------------------------------------------------------- K5: replay with carry, write fp32 out
__global__ __launch_bounds__(256) void scan3_k(const _Float16* __restrict__ G,
                                               const float* __restrict__ Carry,
                                               float* __restrict__ Out) {
  int d = (blockIdx.x * blockDim.x + threadIdx.x) * 2;
  int c = blockIdx.y, b = blockIdx.z;
  int64_t row0 = (int64_t)(b * Ss + c * LCH);
  const _Float16* g = G + row0 * Ndim + d;
  float* o = Out + row0 * Dd + d;
  int co = (b * CH + c) * Dd + d;
  float h0 = Carry[co], h1 = Carry[co + 1];
  for (int s = 0; s < LCH; ++s) {
    half2v fg = *(const half2v*)(g);
    half2v ig = *(const half2v*)(g + Dd);
    half2v hg = *(const half2v*)(g + 2 * Dd);
    float fw, v;
    gate_fv((float)fg[0], (float)ig[0], (float)hg[0], fw, v);
    h0 = fmaf(fw, h0, v);
    gate_fv((float)fg[1], (float)ig[1], (float)hg[1], fw, v);
    h1 = fmaf(fw, h1, v);
    *(float2*)o = make_float2(h0, h1);
    g += Ndim;
    o += Dd;
  }
}

// ---------------------------------------------------------------- launch
extern "C" void kernel_launch(void* const* d_in, const int* in_sizes, int n_in,
                              void* d_out, int out_size, void* d_ws, size_t ws_size,
                              hipStream_t stream) {
  const float* x = (const float*)d_in[0];   // [B,S,D] fp32
  const float* W = (const float*)d_in[1];   // [D,3D] fp32
  float* out = (float*)d_out;               // [B,S,D] fp32

  char* ws = (char*)d_ws;
  size_t off = 0;
  auto alloc = [&](size_t bytes) {
    char* p = ws + off;
    off += (bytes + 255) & ~size_t(255);
    return p;
  };
  _Float16* x16    = (_Float16*)alloc((size_t)Mdim * Kdim * 2);       // 32 MiB
  _Float16* w16t   = (_Float16*)alloc((size_t)Ndim * Kdim * 2);       // 6 MiB
  _Float16* gates  = (_Float16*)alloc((size_t)Mdim * Ndim * 2);       // 96 MiB
  float* Fc        = (float*)alloc((size_t)Bb * CH * Dd * 4);         // 1 MiB
  float* Hc        = (float*)alloc((size_t)Bb * CH * Dd * 4);
  float* Carry     = (float*)alloc((size_t)Bb * CH * Dd * 4);
  if (off > ws_size) return;  // workspace too small: fail cleanly

  cvt_x_k<<<2048, 256, 0, stream>>>(x, x16, Mdim * Kdim / 4);
  cvt_wT_k<<<dim3(Ndim / 32, Kdim / 32), 256, 0, stream>>>(W, w16t);
  gemm8_k<<<dim3((Mdim / GBM) * (Ndim / GBN)), 512, 131072, stream>>>(x16, w16t, gates);
  scan1_k<<<dim3(Dd / 512, CH, Bb), 256, 0, stream>>>(gates, Fc, Hc);
  scan2_k<<<(Bb * Dd) / 256, 256, 0, stream>>>(Fc, Hc, Carry);
  scan3_k<<<dim3(Dd / 512, CH, Bb), 256, 0, stream>>>(gates, Carry, out);
}

// Round 5
// 193.263 us; speedup vs baseline: 2.0689x; 1.0387x over previous
//
#include <hip/hip_runtime.h>
#include <hip/hip_fp16.h>
#include <cstdint>

typedef _Float16 half8  __attribute__((ext_vector_type(8)));
typedef _Float16 half4v __attribute__((ext_vector_type(4)));
typedef _Float16 half2v __attribute__((ext_vector_type(2)));
typedef float    floatx4 __attribute__((ext_vector_type(4)));

// problem dims (fixed by setup_inputs)
constexpr int Bb = 4, Ss = 4096, Dd = 1024;
constexpr int Mdim = Bb * Ss;          // 16384
constexpr int Ndim = 3 * Dd;           // 3072
constexpr int Kdim = Dd;               // 1024
constexpr int CH = 128, LCH = Ss / CH; // 128 chunks of 32

// ---------------------------------------------------------------- utils
__device__ __forceinline__ void gload_lds16(const void* g, void* l) {
  __builtin_amdgcn_global_load_lds(
      (const __attribute__((address_space(1))) uint32_t*)g,
      (__attribute__((address_space(3))) uint32_t*)l, 16, 0, 0);
}

// gate math: fw = sig(f)/(sig(f)+sig(i)) = (1+e^-i)/(2+e^-f+e^-i)
//            iw = (1+e^-f)/(2+e^-f+e^-i);  v = iw * g~(h)
__device__ __forceinline__ void gate_fv(float fg, float ig, float hg,
                                        float& fw, float& v) {
  float ef = __expf(fminf(-fg, 40.f));
  float ei = __expf(fminf(-ig, 40.f));
  float r  = __builtin_amdgcn_rcpf(2.f + ef + ei);
  fw = (1.f + ei) * r;
  float iw = (1.f + ef) * r;
  float g  = hg >= 0.f ? hg + 0.5f
                       : __builtin_amdgcn_rcpf(1.f + __expf(fminf(-hg, 40.f)));
  v = iw * g;
}

// ---------------------------------------------------------------- K0a: x fp32 -> fp16
__global__ __launch_bounds__(256) void cvt_x_k(const float* __restrict__ X,
                                               _Float16* __restrict__ X16, int n4) {
  for (int i = blockIdx.x * blockDim.x + threadIdx.x; i < n4;
       i += gridDim.x * blockDim.x) {
    float4 v = ((const float4*)X)[i];
    half4v o = {(_Float16)v.x, (_Float16)v.y, (_Float16)v.z, (_Float16)v.w};
    ((half4v*)X16)[i] = o;
  }
}

// ---------------------------------------------------------------- K0b: W [K][N] fp32 -> WT [N][K] fp16
__global__ __launch_bounds__(256) void cvt_wT_k(const float* __restrict__ W,
                                                _Float16* __restrict__ WT) {
  __shared__ float tile[32][33];
  int tx = threadIdx.x & 31, ty = threadIdx.x >> 5;  // 32 x 8
  int n0 = blockIdx.x * 32, k0 = blockIdx.y * 32;
#pragma unroll
  for (int j = 0; j < 4; ++j) {
    int k = ty + j * 8;
    tile[k][tx] = W[(int64_t)(k0 + k) * Ndim + n0 + tx];
  }
  __syncthreads();
#pragma unroll
  for (int j = 0; j < 4; ++j) {
    int nl = ty + j * 8;
    WT[(int64_t)(n0 + nl) * Kdim + k0 + tx] = (_Float16)tile[tx][nl];
  }
}

// ---------------------------------------------------------------- K1: 256x256 GEMM, deep-prefetch 2-barrier/tile
// A: x16 [M][K]; BT: W16T [N][K]; C: gates16 [M][N]. All fp16.
// LDS per buffer (64 KiB): A-half0 | A-half1 | B-half0 | B-half1, each
// 128 rows x 64 cols fp16, row stride 128 B, XOR-swizzled 16B slots:
// slot q of row r holds global col-block (q ^ (r&7)).
constexpr int GBM = 256, GBN = 256, GBK = 64;
constexpr int NT = Kdim / GBK;  // 16 K-tiles

__global__ __launch_bounds__(512, 2) void gemm8_k(const _Float16* __restrict__ A,
                                                  const _Float16* __restrict__ BT,
                                                  _Float16* __restrict__ Cg) {
  extern __shared__ char lds[];  // 131072 bytes
  const int tid = threadIdx.x;
  const int wid = tid >> 6, lane = tid & 63;
  const int wm = wid >> 2, wn = wid & 3;
  const int l15 = lane & 15, lq = lane >> 4;

  // XCD-aware swizzle (768 % 8 == 0 -> simple variant is bijective)
  int wg = blockIdx.x;
  wg = (wg & 7) * 96 + (wg >> 3);
  const int n0 = (wg % 12) * GBN;
  const int m0 = (wg / 12) * GBM;

  // LDS read byte-offsets within a half for ks=0; ks=1 is offset ^ 64
  // (slot(ks=1) = slot(ks=0) ^ 4 under the XOR swizzle).
  int aO[4], bO[2];
#pragma unroll
  for (int mi = 0; mi < 4; ++mi) {
    int r = wm * 64 + mi * 16 + l15;
    aO[mi] = r * 128 + ((lq ^ (r & 7)) << 4);
  }
#pragma unroll
  for (int ni = 0; ni < 2; ++ni) {
    int r = wn * 32 + ni * 16 + l15;
    bO[ni] = r * 128 + ((lq ^ (r & 7)) << 4);
  }

  // staging geometry: thread -> (row srr + 64*round, slot ss); dest linear,
  // source column pre-inverse-swizzled (rule #21)
  const int srr = (wid << 3) + (lane >> 3);
  const int ss = lane & 7;
  const _Float16* Abase = A + (size_t)m0 * Kdim;
  const _Float16* Bbase = BT + (size_t)n0 * Kdim;

  auto stage = [&](const _Float16* gsrc, int ldsHalfBase) {
#pragma unroll
    for (int round = 0; round < 2; ++round) {
      int r = (round << 6) + srr;
      int c = ss ^ (r & 7);
      gload_lds16(gsrc + (size_t)r * Kdim + (c << 3),
                  lds + ldsHalfBase + (round << 13) + (wid << 10));
    }
  };

  floatx4 acc[8][4] = {};

  // prologue: tile0 all 4 halves + tile1 A0,B0  (12 loads/lane-slice)
  stage(Abase, 0);                          // A0(0)
  stage(Bbase, 32768);                      // B0(0)
  stage(Bbase + 128 * Kdim, 49152);         // B1(0)
  stage(Abase + 128 * Kdim, 16384);         // A1(0)
  stage(Abase + 64, 65536);                 // A0(1)
  stage(Bbase + 64, 65536 + 32768);         // B0(1)
  asm volatile("s_waitcnt vmcnt(4)" ::: "memory");  // tile0 fully landed
  __builtin_amdgcn_s_barrier();

  for (int kt = 0; kt < NT; ++kt) {
    const int cur = (kt & 1) << 16, nxt = ((kt + 1) & 1) << 16;
    const _Float16* Akt1 = Abase + (kt + 1) * GBK;
    const _Float16* Bkt1 = Bbase + (kt + 1) * GBK;
    const _Float16* Akt2 = Abase + (kt + 2) * GBK;
    const _Float16* Bkt2 = Bbase + (kt + 2) * GBK;

    half8 a[4][2], b0[2][2], b1[2][2];

    // ---- issue reads: A0(8), B0(4), B1(4) — B halves cached for whole tile
#pragma unroll
    for (int mi = 0; mi < 4; ++mi)
#pragma unroll
      for (int ks = 0; ks < 2; ++ks)
        a[mi][ks] = *(const half8*)(lds + cur + (aO[mi] ^ (ks << 6)));
#pragma unroll
    for (int ni = 0; ni < 2; ++ni)
#pragma unroll
      for (int ks = 0; ks < 2; ++ks) {
        b0[ni][ks] = *(const half8*)(lds + cur + 32768 + (bO[ni] ^ (ks << 6)));
        b1[ni][ks] = *(const half8*)(lds + cur + 49152 + (bO[ni] ^ (ks << 6)));
      }
    if (kt + 1 < NT) stage(Bkt1 + 128 * Kdim, nxt + 49152);  // s0: B1(kt+1)

    // ---- Q0 = A0 x B0
    __builtin_amdgcn_s_setprio(1);
#pragma unroll
    for (int ks = 0; ks < 2; ++ks)
#pragma unroll
      for (int mi = 0; mi < 4; ++mi)
#pragma unroll
        for (int ni = 0; ni < 2; ++ni)
          acc[mi][ni] = __builtin_amdgcn_mfma_f32_16x16x32_f16(
              a[mi][ks], b0[ni][ks], acc[mi][ni], 0, 0, 0);
    __builtin_amdgcn_s_setprio(0);
    if (kt + 1 < NT) stage(Akt1 + 128 * Kdim, nxt + 16384);  // s1: A1(kt+1)

    // ---- Q1 = A0 x B1
    __builtin_amdgcn_s_setprio(1);
#pragma unroll
    for (int ks = 0; ks < 2; ++ks)
#pragma unroll
      for (int mi = 0; mi < 4; ++mi)
#pragma unroll
        for (int ni = 0; ni < 2; ++ni)
          acc[mi][2 + ni] = __builtin_amdgcn_mfma_f32_16x16x32_f16(
              a[mi][ks], b1[ni][ks], acc[mi][2 + ni], 0, 0, 0);
    __builtin_amdgcn_s_setprio(0);

    // mid barrier: all waves' cur A0/B0 reads complete (pre-Q0) before restage
    __builtin_amdgcn_s_barrier();

    // ---- A1 reads (reuse a[] regs; A0 dead after Q1)
#pragma unroll
    for (int mi = 0; mi < 4; ++mi)
#pragma unroll
      for (int ks = 0; ks < 2; ++ks)
        a[mi][ks] = *(const half8*)(lds + cur + 16384 + (aO[mi] ^ (ks << 6)));
    if (kt + 2 < NT) stage(Akt2, cur + 0);  // s2: A0(kt+2) over dead cur-A0

    // ---- Q2 = A1 x B0
    __builtin_amdgcn_s_setprio(1);
#pragma unroll
    for (int ks = 0; ks < 2; ++ks)
#pragma unroll
      for (int mi = 0; mi < 4; ++mi)
#pragma unroll
        for (int ni = 0; ni < 2; ++ni)
          acc[4 + mi][ni] = __builtin_amdgcn_mfma_f32_16x16x32_f16(
              a[mi][ks], b0[ni][ks], acc[4 + mi][ni], 0, 0, 0);
    __builtin_amdgcn_s_setprio(0);
    if (kt + 2 < NT) stage(Bkt2, cur + 32768);  // s3: B0(kt+2) over dead cur-B0

    // ---- Q3 = A1 x B1
    __builtin_amdgcn_s_setprio(1);
#pragma unroll
    for (int ks = 0; ks < 2; ++ks)
#pragma unroll
      for (int mi = 0; mi < 4; ++mi)
#pragma unroll
        for (int ni = 0; ni < 2; ++ni)
          acc[4 + mi][2 + ni] = __builtin_amdgcn_mfma_f32_16x16x32_f16(
              a[mi][ks], b1[ni][ks], acc[4 + mi][2 + ni], 0, 0, 0);
    __builtin_amdgcn_s_setprio(0);

    // K-tile boundary: counted vmcnt (never 0 mid-loop), then barrier
    if (kt < NT - 2) {
      asm volatile("s_waitcnt vmcnt(4)" ::: "memory");
      __builtin_amdgcn_s_barrier();
    } else if (kt == NT - 2) {
      asm volatile("s_waitcnt vmcnt(0)" ::: "memory");  // drain: no stages left
      __builtin_amdgcn_s_barrier();
    }
  }

  // epilogue: D layout col=l15, row=lq*4+r
#pragma unroll
  for (int mf = 0; mf < 8; ++mf) {
    int row = m0 + ((mf >> 2) << 7) + wm * 64 + ((mf & 3) << 4) + (lq << 2);
#pragma unroll
    for (int nf = 0; nf < 4; ++nf) {
      int col = n0 + ((nf >> 1) << 7) + wn * 32 + ((nf & 1) << 4) + l15;
#pragma unroll
      for (int r = 0; r < 4; ++r)
        Cg[(size_t)(row + r) * Ndim + col] = (_Float16)acc[mf][nf][r];
    }
  }
}

// ---------------------------------------------------------------- K3: per-chunk scan, 4 d-channels/thread
// G: gates [M][3D] fp16. 256 threads cover 1024 d via half4 loads (8 B/lane).
__global__ __launch_bounds__(256) void scan1_k(const _Float16* __restrict__ G,
                                               float* __restrict__ Fc,
                                               float* __restrict__ Hc) {
  int d = threadIdx.x * 4;
  int c = blockIdx.y, b = blockIdx.z;
  const _Float16* g = G + (int64_t)(b * Ss + c * LCH) * Ndim + d;
  float h[4] = {0.f, 0.f, 0.f, 0.f};
  float F[4] = {1.f, 1.f, 1.f, 1.f};
#pragma unroll 4
  for (int s = 0; s < LCH; ++s) {
    half4v fg = *(const half4v*)(g);
    half4v ig = *(const half4v*)(g + Dd);
    half4v hg = *(const half4v*)(g + 2 * Dd);
#pragma unroll
    for (int j = 0; j < 4; ++j) {
      float fw, v;
      gate_fv((float)fg[j], (float)ig[j], (float)hg[j], fw, v);
      h[j] = fmaf(fw, h[j], v);
      F[j] *= fw;
    }
    g += Ndim;
  }
  int co = (b * CH + c) * Dd + d;
  *(floatx4*)(Fc + co) = *(floatx4*)F;
  *(floatx4*)(Hc + co) = *(floatx4*)h;
}

// ---------------------------------------------------------------- K4: chunk-carry scan (tiny)
__global__ __launch_bounds__(256) void scan2_k(const float* __restrict__ Fc,
                                               const float* __restrict__ Hc,
                                               float* __restrict__ Carry) {
  int idx = blockIdx.x * 256 + threadIdx.x;  // 0..4095
  int b = idx >> 10, d = idx & (Dd - 1);
  float carry = 0.f;
#pragma unroll 8
  for (int c = 0; c < CH; ++c) {
    int co = (b * CH + c) * Dd + d;
    Carry[co] = carry;
    carry = fmaf(Fc[co], carry, Hc[co]);
  }
}

// ---------------------------------------------------------------- K5: replay with carry, write fp32 out
__global__ __launch_bounds__(256) void scan3_k(const _Float16* __restrict__ G,
                                               const float* __restrict__ Carry,
                                               float* __restrict__ Out) {
  int d = threadIdx.x * 4;
  int c = blockIdx.y, b = blockIdx.z;
  int64_t row0 = (int64_t)(b * Ss + c * LCH);
  const _Float16* g = G + row0 * Ndim + d;
  float* o = Out + row0 * Dd + d;
  int co = (b * CH + c) * Dd + d;
  floatx4 hv = *(const floatx4*)(Carry + co);
  float h[4] = {hv[0], hv[1], hv[2], hv[3]};
#pragma unroll 4
  for (int s = 0; s < LCH; ++s) {
    half4v fg = *(const half4v*)(g);
    half4v ig = *(const half4v*)(g + Dd);
    half4v hg = *(const half4v*)(g + 2 * Dd);
#pragma unroll
    for (int j = 0; j < 4; ++j) {
      float fw, v;
      gate_fv((float)fg[j], (float)ig[j], (float)hg[j], fw, v);
      h[j] = fmaf(fw, h[j], v);
    }
    *(floatx4*)o = *(floatx4*)h;
    g += Ndim;
    o += Dd;
  }
}

// ---------------------------------------------------------------- launch
extern "C" void kernel_launch(void* const* d_in, const int* in_sizes, int n_in,
                              void* d_out, int out_size, void* d_ws, size_t ws_size,
                              hipStream_t stream) {
  const float* x = (const float*)d_in[0];   // [B,S,D] fp32
  const float* W = (const float*)d_in[1];   // [D,3D] fp32
  float* out = (float*)d_out;               // [B,S,D] fp32

  char* ws = (char*)d_ws;
  size_t off = 0;
  auto alloc = [&](size_t bytes) {
    char* p = ws + off;
    off += (bytes + 255) & ~size_t(255);
    return p;
  };
  _Float16* x16    = (_Float16*)alloc((size_t)Mdim * Kdim * 2);       // 32 MiB
  _Float16* w16t   = (_Float16*)alloc((size_t)Ndim * Kdim * 2);       // 6 MiB
  _Float16* gates  = (_Float16*)alloc((size_t)Mdim * Ndim * 2);       // 96 MiB
  float* Fc        = (float*)alloc((size_t)Bb * CH * Dd * 4);         // 2 MiB
  float* Hc        = (float*)alloc((size_t)Bb * CH * Dd * 4);
  float* Carry     = (float*)alloc((size_t)Bb * CH * Dd * 4);
  if (off > ws_size) return;  // workspace too small: fail cleanly

  cvt_x_k<<<2048, 256, 0, stream>>>(x, x16, Mdim * Kdim / 4);
  cvt_wT_k<<<dim3(Ndim / 32, Kdim / 32), 256, 0, stream>>>(W, w16t);
  gemm8_k<<<dim3((Mdim / GBM) * (Ndim / GBN)), 512, 131072, stream>>>(x16, w16t, gates);
  scan1_k<<<dim3(1, CH, Bb), 256, 0, stream>>>(gates, Fc, Hc);
  scan2_k<<<(Bb * Dd) / 256, 256, 0, stream>>>(Fc, Hc, Carry);
  scan3_k<<<dim3(1, CH, Bb), 256, 0, stream>>>(gates, Carry, out);
}